// Round 3
// baseline (243.936 us; speedup 1.0000x reference)
//
#include <hip/hip_runtime.h>
#include <stdint.h>

// YOLO loss R9: direct per-lane AoS loads -- zero LDS, zero staging.
// History (per-dispatch): R5 66us (coalesced+LDS), R6 ~50us (+NT),
// R7 65.7us (gld_lds, no NT), R8 ~51us (NT + constant 15-deep pipeline).
// Depth/occupancy/DMA all neutral at fixed cache policy -> the last shared
// structure is the coalesced->LDS->ds_read redistribution itself. Cell data
// is AoS-contiguous (30f/25f per cell), so per-lane direct loads touch the
// SAME cache-line set as coalesced loads (dense stream, same FETCH) while
// deleting every wait/drain/ds op. Dynamic best-box index -> cndmask selects
// (no runtime register indexing). 3136 blocks x 256 thr = exactly 802816
// cells, one per thread, no loop.
// Predict: main 50 -> 30-38us, total ~162-170, LDS=0, bank-conflict=0,
// VGPR ~100. If main pins ~50us -> read-return-path cap confirmed ->
// policy sweep or roofline.

#define NCLS   20
#define SLOTS  128
#define CELLS  802816
#define NBLK   3136          // 3136 * 256 == 802816 exactly

typedef float f4 __attribute__((ext_vector_type(4)));
typedef float f2 __attribute__((ext_vector_type(2)));
typedef f4 f4a __attribute__((aligned(4)));   // cell bases are only 4B/8B aligned
typedef f2 f2a __attribute__((aligned(4)));

__global__ __launch_bounds__(256) void yolo_main(
    const float* __restrict__ pred,
    const float* __restrict__ target,
    float* __restrict__ ws)
{
    const int g = blockIdx.x * 256 + threadIdx.x;   // cell id, always < CELLS

    const float* p = pred   + (size_t)g * 30;       // 120B window, 8B aligned
    const float* t = target + (size_t)g * 25;       // 100B window, 4B aligned

    // ---- issue all 15 NT loads back-to-back (14KB/wave in flight)
    f4a q0 = __builtin_nontemporal_load((const f4a*)(p +  0));
    f4a q1 = __builtin_nontemporal_load((const f4a*)(p +  4));
    f4a q2 = __builtin_nontemporal_load((const f4a*)(p +  8));
    f4a q3 = __builtin_nontemporal_load((const f4a*)(p + 12));
    f4a q4 = __builtin_nontemporal_load((const f4a*)(p + 16));
    f4a q5 = __builtin_nontemporal_load((const f4a*)(p + 20));
    f4a q6 = __builtin_nontemporal_load((const f4a*)(p + 24));
    f2a q7 = __builtin_nontemporal_load((const f2a*)(p + 28));

    f4a u0 = __builtin_nontemporal_load((const f4a*)(t +  0));
    f4a u1 = __builtin_nontemporal_load((const f4a*)(t +  4));
    f4a u2 = __builtin_nontemporal_load((const f4a*)(t +  8));
    f4a u3 = __builtin_nontemporal_load((const f4a*)(t + 12));
    f4a u4 = __builtin_nontemporal_load((const f4a*)(t + 16));
    f4a u5 = __builtin_nontemporal_load((const f4a*)(t + 20));
    float u6 = __builtin_nontemporal_load(t + 24);

    // ---- unpack (all static indices -> stays in VGPRs)
    float P[30];
    #pragma unroll
    for (int j = 0; j < 4; ++j) {
        P[ 0 + j] = q0[j]; P[ 4 + j] = q1[j]; P[ 8 + j] = q2[j];
        P[12 + j] = q3[j]; P[16 + j] = q4[j]; P[20 + j] = q5[j];
        P[24 + j] = q6[j];
    }
    P[28] = q7[0]; P[29] = q7[1];

    float T[25];
    #pragma unroll
    for (int j = 0; j < 4; ++j) {
        T[ 0 + j] = u0[j]; T[ 4 + j] = u1[j]; T[ 8 + j] = u2[j];
        T[12 + j] = u3[j]; T[16 + j] = u4[j]; T[20 + j] = u5[j];
    }
    T[24] = u6;

    // ---- per-cell loss (identical math to verified R5..R8 lineage)
    const float EPS = 1e-6f;

    const float tobj = T[20];
    const float tx = T[21], ty = T[22], tw = T[23], th = T[24];

    const float t_x1 = tx - tw * 0.5f, t_x2 = tx + tw * 0.5f;
    const float t_y1 = ty - th * 0.5f, t_y2 = ty + th * 0.5f;
    const float t_area = fabsf((t_x2 - t_x1) * (t_y2 - t_y1));

    float iou[2];
    #pragma unroll
    for (int b = 0; b < 2; ++b) {
        const float bx = P[NCLS + 5 * b + 1];
        const float by = P[NCLS + 5 * b + 2];
        const float bw = P[NCLS + 5 * b + 3];
        const float bh = P[NCLS + 5 * b + 4];
        const float x1 = bx - bw * 0.5f, x2 = bx + bw * 0.5f;
        const float y1 = by - bh * 0.5f, y2 = by + bh * 0.5f;
        const float iw = fmaxf(fminf(x2, t_x2) - fmaxf(x1, t_x1), 0.0f);
        const float ih = fmaxf(fminf(y2, t_y2) - fmaxf(y1, t_y1), 0.0f);
        const float inter = iw * ih;
        const float a1 = fabsf((x2 - x1) * (y2 - y1));
        iou[b] = inter / (a1 + t_area - inter + EPS);
    }
    const bool sel = iou[1] > iou[0];

    // static-index both candidates, select with cndmask (no runtime reg index)
    const float bconf = sel ? P[25] : P[20];
    const float bxv   = sel ? P[26] : P[21];
    const float byv   = sel ? P[27] : P[22];
    const float bwv   = sel ? P[28] : P[23];
    const float bhv   = sel ? P[29] : P[24];

    const float sgnw = (bwv > 0.f) ? 1.f : ((bwv < 0.f) ? -1.f : 0.f);
    const float sgnh = (bhv > 0.f) ? 1.f : ((bhv < 0.f) ? -1.f : 0.f);
    const float swv = sgnw * sqrtf(fabsf(bwv) + EPS);
    const float shv = sgnh * sqrtf(fabsf(bhv) + EPS);

    float d0 = tobj * bxv - tobj * tx;
    float d1 = tobj * byv - tobj * ty;
    float d2 = tobj * swv - sqrtf(fmaxf(tobj * tw, 0.0f));
    float d3 = tobj * shv - sqrtf(fmaxf(tobj * th, 0.0f));
    float box_loss = d0 * d0 + d1 * d1 + d2 * d2 + d3 * d3;

    const float noobj = 1.0f - tobj;
    float n0 = noobj * (P[NCLS + 0] - tobj);
    float n1 = noobj * (P[NCLS + 5] - tobj);
    float no_object_loss = n0 * n0 + n1 * n1;

    float od = tobj * (bconf - tobj);
    float object_loss = od * od;

    float class_loss = 0.0f;
    #pragma unroll
    for (int k = 0; k < NCLS; ++k) {
        float cd = tobj * (P[k] - T[k]);
        class_loss += cd * cd;
    }

    float acc = 5.0f * box_loss + object_loss
              + 0.5f * no_object_loss + class_loss;

    // ---- wave reduce + one spread atomic per wave
    #pragma unroll
    for (int off = 32; off > 0; off >>= 1)
        acc += __shfl_down(acc, off, 64);

    if ((threadIdx.x & 63) == 0)
        atomicAdd(&ws[(g >> 6) & (SLOTS - 1)], acc);
}

__global__ __launch_bounds__(64) void yolo_reduce(
    const float* __restrict__ ws, float* __restrict__ out)
{
    const int lane = threadIdx.x;
    float s = ws[lane] + ws[lane + 64];
    #pragma unroll
    for (int off = 32; off > 0; off >>= 1)
        s += __shfl_down(s, off, 64);
    if (lane == 0) out[0] = s;
}

extern "C" void kernel_launch(void* const* d_in, const int* in_sizes, int n_in,
                              void* d_out, int out_size, void* d_ws, size_t ws_size,
                              hipStream_t stream) {
    const float* pred   = (const float*)d_in[0];
    const float* target = (const float*)d_in[1];
    float* ws  = (float*)d_ws;
    float* out = (float*)d_out;

    hipMemsetAsync(ws, 0, SLOTS * sizeof(float), stream);

    hipLaunchKernelGGL(yolo_main, dim3(NBLK), dim3(256), 0, stream,
                       pred, target, ws);
    hipLaunchKernelGGL(yolo_reduce, dim3(1), dim3(64), 0, stream, ws, out);
}

// Round 4
// 196.874 us; speedup vs baseline: 1.2390x; 1.2390x over previous
//
#include <hip/hip_runtime.h>
#include <stdint.h>

// YOLO loss R10: sc1 (device-scope) loads -- bypass per-XCD L2, serve from
// Infinity Cache (L3) where the re-poison fills just left the input.
// Policy map measured so far (coalesced, per-dispatch):
//   plain (L2-allocating): 2.7 TB/s (R5 66us, R7 65.7us; FETCH 86MB)
//   nt    (L3-bypassing) : 3.5 TB/s (R6 ~50us, R8 ~51us)
//   nt + per-lane AoS    : 2.4 TB/s, FETCH 226MB (R9 -- NT misses dirty L3,
//                          16B/lane amplifies sectors)
// sc1 is the untested quadrant: L3-hitting WITHOUT L2 allocation. Skeleton
// is R8's verified structure (reg double-buffer, 15 loads/tile, counted
// vmcnt(15), LDS redistribute, single-wave blocks); only the load flavor
// changes. Inline-asm loads are invisible to compiler waitcnt tracking ->
// explicit s_waitcnt vmcnt(N) + sched_barrier(0) before each drain.
// Predict: main 36-44us, FETCH ~86MB. If ~50us -> sc1==nt (fabric cap,
// near-roofline). If ~65us -> sc1==plain (L2-alloc theory dies).

#define NCLS   20
#define SLOTS  128
#define GRID   2048          // 8 blocks/CU x 256 CU
#define TILES  12544         // 802816 cells / 64 cells per tile
#define PRED_F 1920          // floats per pred tile (64 cells x 30)
#define TGT_F  1600          // floats per target tile (64 cells x 25)

typedef float f4 __attribute__((ext_vector_type(4)));

__device__ static inline f4 ldg4_sc1(const float* p) {
    f4 r;
    asm volatile("global_load_dwordx4 %0, %1, off sc1"
                 : "=v"(r) : "v"(p));
    return r;
}

struct Tile {
    f4 rp[8];   // pred: 7 full-wave 1024B chunks + 1 half-wave (lane<32)
    f4 rt[7];   // tgt : 6 full-wave 1024B chunks + 1 quarter-wave (lane<16)
};

// 15 load INSTRUCTIONS per tile (vmcnt unit is per-wave; masked lanes
// still count the instruction once).
__device__ static inline void load_tile(Tile& T,
                                        const float* __restrict__ pred,
                                        const float* __restrict__ target,
                                        int tile, int lane)
{
    const float* gp = pred   + (size_t)tile * PRED_F;
    const float* gt = target + (size_t)tile * TGT_F;
    #pragma unroll
    for (int c = 0; c < 7; ++c) T.rp[c] = ldg4_sc1(gp + lane * 4 + c * 256);
    if (lane < 32) T.rp[7] = ldg4_sc1(gp + lane * 4 + 7 * 256);
    #pragma unroll
    for (int c = 0; c < 6; ++c) T.rt[c] = ldg4_sc1(gt + lane * 4 + c * 256);
    if (lane < 16) T.rt[6] = ldg4_sc1(gt + lane * 4 + 6 * 256);
}

__device__ static inline void drain_tile(const Tile& T, float* sp, float* st,
                                         int lane)
{
    #pragma unroll
    for (int c = 0; c < 7; ++c) *(f4*)(sp + lane * 4 + c * 256) = T.rp[c];
    if (lane < 32) *(f4*)(sp + lane * 4 + 7 * 256) = T.rp[7];
    #pragma unroll
    for (int c = 0; c < 6; ++c) *(f4*)(st + lane * 4 + c * 256) = T.rt[c];
    if (lane < 16) *(f4*)(st + lane * 4 + 6 * 256) = T.rt[6];
}

__device__ static inline float compute_cell(const float* lp, const float* lt)
{
    const float EPS = 1e-6f;

    const float tobj = lt[20];
    const float tx = lt[21], ty = lt[22], tw = lt[23], th = lt[24];

    const float t_x1 = tx - tw * 0.5f, t_x2 = tx + tw * 0.5f;
    const float t_y1 = ty - th * 0.5f, t_y2 = ty + th * 0.5f;
    const float t_area = fabsf((t_x2 - t_x1) * (t_y2 - t_y1));

    float iou[2];
    #pragma unroll
    for (int b = 0; b < 2; ++b) {
        const float bx = lp[NCLS + 5 * b + 1];
        const float by = lp[NCLS + 5 * b + 2];
        const float bw = lp[NCLS + 5 * b + 3];
        const float bh = lp[NCLS + 5 * b + 4];
        const float x1 = bx - bw * 0.5f, x2 = bx + bw * 0.5f;
        const float y1 = by - bh * 0.5f, y2 = by + bh * 0.5f;
        const float iw = fmaxf(fminf(x2, t_x2) - fmaxf(x1, t_x1), 0.0f);
        const float ih = fmaxf(fminf(y2, t_y2) - fmaxf(y1, t_y1), 0.0f);
        const float inter = iw * ih;
        const float a1 = fabsf((x2 - x1) * (y2 - y1));
        iou[b] = inter / (a1 + t_area - inter + EPS);
    }
    const int best = (iou[1] > iou[0]) ? 1 : 0;

    const float bconf = lp[NCLS + 5 * best + 0];
    const float bxv   = lp[NCLS + 5 * best + 1];
    const float byv   = lp[NCLS + 5 * best + 2];
    const float bwv   = lp[NCLS + 5 * best + 3];
    const float bhv   = lp[NCLS + 5 * best + 4];

    const float sgnw = (bwv > 0.f) ? 1.f : ((bwv < 0.f) ? -1.f : 0.f);
    const float sgnh = (bhv > 0.f) ? 1.f : ((bhv < 0.f) ? -1.f : 0.f);
    const float swv = sgnw * sqrtf(fabsf(bwv) + EPS);
    const float shv = sgnh * sqrtf(fabsf(bhv) + EPS);

    float d0 = tobj * bxv - tobj * tx;
    float d1 = tobj * byv - tobj * ty;
    float d2 = tobj * swv - sqrtf(fmaxf(tobj * tw, 0.0f));
    float d3 = tobj * shv - sqrtf(fmaxf(tobj * th, 0.0f));
    float box_loss = d0 * d0 + d1 * d1 + d2 * d2 + d3 * d3;

    const float noobj = 1.0f - tobj;
    float n0 = noobj * (lp[NCLS + 0] - tobj);
    float n1 = noobj * (lp[NCLS + 5] - tobj);
    float no_object_loss = n0 * n0 + n1 * n1;

    float od = tobj * (bconf - tobj);
    float object_loss = od * od;

    float class_loss = 0.0f;
    #pragma unroll
    for (int k = 0; k < NCLS; ++k) {
        float cd = tobj * (lp[k] - lt[k]);
        class_loss += cd * cd;
    }

    return 5.0f * box_loss + object_loss + 0.5f * no_object_loss + class_loss;
}

__global__ __launch_bounds__(64, 2) void yolo_main(
    const float* __restrict__ pred,
    const float* __restrict__ target,
    float* __restrict__ ws)
{
    __shared__ float sp[PRED_F];   // 7,680 B
    __shared__ float st[TGT_F];    // 6,400 B

    const int lane = threadIdx.x;
    const int blk  = blockIdx.x;
    const int n = (TILES - blk + GRID - 1) / GRID;   // 7 (blk<256) or 6

    Tile A, B;
    load_tile(A, pred, target, blk, lane);           // 15 in flight

    float acc = 0.0f;
    int i = 0;

    while (true) {
        // A holds tile i. Issue i+1 into B, THEN wait for A only (vmcnt 15).
        if (i + 1 < n) {
            load_tile(B, pred, target, blk + (i + 1) * GRID, lane);
            asm volatile("s_waitcnt vmcnt(15)" ::: "memory");
        } else {
            asm volatile("s_waitcnt vmcnt(0)" ::: "memory");
        }
        __builtin_amdgcn_sched_barrier(0);   // keep drain below the wait
        drain_tile(A, sp, st, lane);
        acc += compute_cell(sp + lane * 30, st + lane * 25);
        __asm__ volatile("" ::: "memory");   // LDS reads stay in this iter
        if (++i >= n) break;

        // B holds tile i. Mirror phase.
        if (i + 1 < n) {
            load_tile(A, pred, target, blk + (i + 1) * GRID, lane);
            asm volatile("s_waitcnt vmcnt(15)" ::: "memory");
        } else {
            asm volatile("s_waitcnt vmcnt(0)" ::: "memory");
        }
        __builtin_amdgcn_sched_barrier(0);
        drain_tile(B, sp, st, lane);
        acc += compute_cell(sp + lane * 30, st + lane * 25);
        __asm__ volatile("" ::: "memory");
        if (++i >= n) break;
    }

    // wave reduce + one spread atomic per wave
    #pragma unroll
    for (int off = 32; off > 0; off >>= 1)
        acc += __shfl_down(acc, off, 64);

    if (lane == 0)
        atomicAdd(&ws[blk & (SLOTS - 1)], acc);
}

__global__ __launch_bounds__(64) void yolo_reduce(
    const float* __restrict__ ws, float* __restrict__ out)
{
    const int lane = threadIdx.x;
    float s = ws[lane] + ws[lane + 64];
    #pragma unroll
    for (int off = 32; off > 0; off >>= 1)
        s += __shfl_down(s, off, 64);
    if (lane == 0) out[0] = s;
}

extern "C" void kernel_launch(void* const* d_in, const int* in_sizes, int n_in,
                              void* d_out, int out_size, void* d_ws, size_t ws_size,
                              hipStream_t stream) {
    const float* pred   = (const float*)d_in[0];
    const float* target = (const float*)d_in[1];
    float* ws  = (float*)d_ws;
    float* out = (float*)d_out;

    hipMemsetAsync(ws, 0, SLOTS * sizeof(float), stream);

    hipLaunchKernelGGL(yolo_main, dim3(GRID), dim3(64), 0, stream,
                       pred, target, ws);
    hipLaunchKernelGGL(yolo_reduce, dim3(1), dim3(64), 0, stream, ws, out);
}

// Round 5
// 191.989 us; speedup vs baseline: 1.2706x; 1.0254x over previous
//
#include <hip/hip_runtime.h>
#include <stdint.h>

// YOLO loss R11: DUAL-PATH read test -- pred via NT (streaming/bypass path,
// caps ~3.5 TB/s), target via plain (L2-allocating path, caps ~2.7 TB/s),
// both in flight in every window.
// Evidence so far: R10's cache-resident replay (hbm_bytes=65KB) still took
// 66.4us -> plain-path cap is SOURCE-INSENSITIVE (a per-CU return-rate cap,
// ~4.4 B/cy/CU), not an HBM/L2 limit. NT path caps ~5.7 B/cy/CU (R6/R8
// ~51us). Fills WRITE at 6.8 TB/s; m13's 6.29 "copy BW" is R+W => pure-read
// ~3.15 -- right at the NT pin. Reads cap per-PATH. If the two paths are
// separate hardware queues, concurrent use sums: 2.7+3.5 ~= 6.2 TB/s.
// Split is within-tile (pred 8 NT instrs + target 7 plain instrs) so both
// pools are occupied simultaneously -- alternating by tile would not test
// additivity. Skeleton = R8's verified structure.
// Predict: separate pools -> main 31-36us, FETCH ~135MB. Shared pool ->
// main 56-60us (blend 3.09 TB/s). If shared: restore R8, declare read-path
// roofline next round.

#define NCLS   20
#define SLOTS  128
#define GRID   2048          // 8 blocks/CU x 256 CU
#define TILES  12544         // 802816 cells / 64 cells per tile
#define PRED_F 1920          // floats per pred tile (64 cells x 30)
#define TGT_F  1600          // floats per target tile (64 cells x 25)

typedef float f4 __attribute__((ext_vector_type(4)));

__device__ static inline f4 ldg4nt(const float* p) {
    return __builtin_nontemporal_load((const f4*)p);
}
__device__ static inline f4 ldg4(const float* p) {
    return *(const f4*)p;
}

struct Tile {
    f4 rp[8];   // pred: 7 full-wave 1024B chunks + 1 half-wave (lane<32)
    f4 rt[7];   // tgt : 6 full-wave 1024B chunks + 1 quarter-wave (lane<16)
};

__device__ static inline void load_tile(Tile& T,
                                        const float* __restrict__ pred,
                                        const float* __restrict__ target,
                                        int tile, int lane)
{
    const float* gp = pred   + (size_t)tile * PRED_F;
    const float* gt = target + (size_t)tile * TGT_F;
    // pred -> NT (streaming path)
    #pragma unroll
    for (int c = 0; c < 7; ++c) T.rp[c] = ldg4nt(gp + lane * 4 + c * 256);
    if (lane < 32) T.rp[7] = ldg4nt(gp + lane * 4 + 7 * 256);
    // target -> plain (L2-allocating path)
    #pragma unroll
    for (int c = 0; c < 6; ++c) T.rt[c] = ldg4(gt + lane * 4 + c * 256);
    if (lane < 16) T.rt[6] = ldg4(gt + lane * 4 + 6 * 256);
}

__device__ static inline void drain_tile(const Tile& T, float* sp, float* st,
                                         int lane)
{
    #pragma unroll
    for (int c = 0; c < 7; ++c) *(f4*)(sp + lane * 4 + c * 256) = T.rp[c];
    if (lane < 32) *(f4*)(sp + lane * 4 + 7 * 256) = T.rp[7];
    #pragma unroll
    for (int c = 0; c < 6; ++c) *(f4*)(st + lane * 4 + c * 256) = T.rt[c];
    if (lane < 16) *(f4*)(st + lane * 4 + 6 * 256) = T.rt[6];
}

__device__ static inline float compute_cell(const float* lp, const float* lt)
{
    const float EPS = 1e-6f;

    const float tobj = lt[20];
    const float tx = lt[21], ty = lt[22], tw = lt[23], th = lt[24];

    const float t_x1 = tx - tw * 0.5f, t_x2 = tx + tw * 0.5f;
    const float t_y1 = ty - th * 0.5f, t_y2 = ty + th * 0.5f;
    const float t_area = fabsf((t_x2 - t_x1) * (t_y2 - t_y1));

    float iou[2];
    #pragma unroll
    for (int b = 0; b < 2; ++b) {
        const float bx = lp[NCLS + 5 * b + 1];
        const float by = lp[NCLS + 5 * b + 2];
        const float bw = lp[NCLS + 5 * b + 3];
        const float bh = lp[NCLS + 5 * b + 4];
        const float x1 = bx - bw * 0.5f, x2 = bx + bw * 0.5f;
        const float y1 = by - bh * 0.5f, y2 = by + bh * 0.5f;
        const float iw = fmaxf(fminf(x2, t_x2) - fmaxf(x1, t_x1), 0.0f);
        const float ih = fmaxf(fminf(y2, t_y2) - fmaxf(y1, t_y1), 0.0f);
        const float inter = iw * ih;
        const float a1 = fabsf((x2 - x1) * (y2 - y1));
        iou[b] = inter / (a1 + t_area - inter + EPS);
    }
    const int best = (iou[1] > iou[0]) ? 1 : 0;

    const float bconf = lp[NCLS + 5 * best + 0];
    const float bxv   = lp[NCLS + 5 * best + 1];
    const float byv   = lp[NCLS + 5 * best + 2];
    const float bwv   = lp[NCLS + 5 * best + 3];
    const float bhv   = lp[NCLS + 5 * best + 4];

    const float sgnw = (bwv > 0.f) ? 1.f : ((bwv < 0.f) ? -1.f : 0.f);
    const float sgnh = (bhv > 0.f) ? 1.f : ((bhv < 0.f) ? -1.f : 0.f);
    const float swv = sgnw * sqrtf(fabsf(bwv) + EPS);
    const float shv = sgnh * sqrtf(fabsf(bhv) + EPS);

    float d0 = tobj * bxv - tobj * tx;
    float d1 = tobj * byv - tobj * ty;
    float d2 = tobj * swv - sqrtf(fmaxf(tobj * tw, 0.0f));
    float d3 = tobj * shv - sqrtf(fmaxf(tobj * th, 0.0f));
    float box_loss = d0 * d0 + d1 * d1 + d2 * d2 + d3 * d3;

    const float noobj = 1.0f - tobj;
    float n0 = noobj * (lp[NCLS + 0] - tobj);
    float n1 = noobj * (lp[NCLS + 5] - tobj);
    float no_object_loss = n0 * n0 + n1 * n1;

    float od = tobj * (bconf - tobj);
    float object_loss = od * od;

    float class_loss = 0.0f;
    #pragma unroll
    for (int k = 0; k < NCLS; ++k) {
        float cd = tobj * (lp[k] - lt[k]);
        class_loss += cd * cd;
    }

    return 5.0f * box_loss + object_loss + 0.5f * no_object_loss + class_loss;
}

__global__ __launch_bounds__(64, 2) void yolo_main(
    const float* __restrict__ pred,
    const float* __restrict__ target,
    float* __restrict__ ws)
{
    __shared__ float sp[PRED_F];   // 7,680 B
    __shared__ float st[TGT_F];    // 6,400 B

    const int lane = threadIdx.x;
    const int blk  = blockIdx.x;
    const int n = (TILES - blk + GRID - 1) / GRID;   // 7 (blk<256) or 6

    Tile A, B;
    load_tile(A, pred, target, blk, lane);

    float acc = 0.0f;
    int i = 0;

    while (true) {
        // A holds tile i; issue tile i+1 into B BEFORE draining A.
        if (i + 1 < n) load_tile(B, pred, target, blk + (i + 1) * GRID, lane);
        __builtin_amdgcn_sched_barrier(0);   // pin load issue before drain
        drain_tile(A, sp, st, lane);
        acc += compute_cell(sp + lane * 30, st + lane * 25);
        __asm__ volatile("" ::: "memory");   // keep LDS reads inside this iter
        if (++i >= n) break;

        // B holds tile i; mirror phase.
        if (i + 1 < n) load_tile(A, pred, target, blk + (i + 1) * GRID, lane);
        __builtin_amdgcn_sched_barrier(0);
        drain_tile(B, sp, st, lane);
        acc += compute_cell(sp + lane * 30, st + lane * 25);
        __asm__ volatile("" ::: "memory");
        if (++i >= n) break;
    }

    // wave reduce + one spread atomic per wave
    #pragma unroll
    for (int off = 32; off > 0; off >>= 1)
        acc += __shfl_down(acc, off, 64);

    if (lane == 0)
        atomicAdd(&ws[blk & (SLOTS - 1)], acc);
}

__global__ __launch_bounds__(64) void yolo_reduce(
    const float* __restrict__ ws, float* __restrict__ out)
{
    const int lane = threadIdx.x;
    float s = ws[lane] + ws[lane + 64];
    #pragma unroll
    for (int off = 32; off > 0; off >>= 1)
        s += __shfl_down(s, off, 64);
    if (lane == 0) out[0] = s;
}

extern "C" void kernel_launch(void* const* d_in, const int* in_sizes, int n_in,
                              void* d_out, int out_size, void* d_ws, size_t ws_size,
                              hipStream_t stream) {
    const float* pred   = (const float*)d_in[0];
    const float* target = (const float*)d_in[1];
    float* ws  = (float*)d_ws;
    float* out = (float*)d_out;

    hipMemsetAsync(ws, 0, SLOTS * sizeof(float), stream);

    hipLaunchKernelGGL(yolo_main, dim3(GRID), dim3(64), 0, stream,
                       pred, target, ws);
    hipLaunchKernelGGL(yolo_reduce, dim3(1), dim3(64), 0, stream, ws, out);
}

// Round 6
// 181.734 us; speedup vs baseline: 1.3423x; 1.0564x over previous
//
#include <hip/hip_runtime.h>
#include <stdint.h>

// YOLO loss R12: last policy quadrant -- nt+sc1 combined (streaming AND
// device-scope). Policy map measured (coalesced, per-dispatch):
//   plain 2.7 TB/s (R5/R7 66us) | sc1 2.7 (R10 67us) | nt 3.5 (R6/R8 ~51us)
//   nt||plain mix ~3.0 (R11 ~60us -> SHARED return pool, rates don't add)
//   R10 replay: input fully L3-resident (FETCH~0) still 66us -> cap is the
//   L2/TCC->CU return path, not the data source.
// Theory: nt's 3.5 pin may still pay per-line L2 probe/transit; sc1 moves
// the coherence point and may let streaming requests skip local-L2
// machinery. Single-variable A/B vs R10 (sc1) and R8 (nt): only the flag
// string changes on the verified R10 skeleton.
// Predict: fast path exists -> main 35-45us. nt+sc1==nt -> main ~51us,
// declare <<ROOFLINE>> next round. sc1 wins the encoding -> main ~66us,
// restore R8 and declare.

#define NCLS   20
#define SLOTS  128
#define GRID   2048          // 8 blocks/CU x 256 CU
#define TILES  12544         // 802816 cells / 64 cells per tile
#define PRED_F 1920          // floats per pred tile (64 cells x 30)
#define TGT_F  1600          // floats per target tile (64 cells x 25)

typedef float f4 __attribute__((ext_vector_type(4)));

__device__ static inline f4 ldg4_ntsc1(const float* p) {
    f4 r;
    asm volatile("global_load_dwordx4 %0, %1, off sc1 nt"
                 : "=v"(r) : "v"(p));
    return r;
}

struct Tile {
    f4 rp[8];   // pred: 7 full-wave 1024B chunks + 1 half-wave (lane<32)
    f4 rt[7];   // tgt : 6 full-wave 1024B chunks + 1 quarter-wave (lane<16)
};

// 15 load INSTRUCTIONS per tile (vmcnt counts instructions per wave).
__device__ static inline void load_tile(Tile& T,
                                        const float* __restrict__ pred,
                                        const float* __restrict__ target,
                                        int tile, int lane)
{
    const float* gp = pred   + (size_t)tile * PRED_F;
    const float* gt = target + (size_t)tile * TGT_F;
    #pragma unroll
    for (int c = 0; c < 7; ++c) T.rp[c] = ldg4_ntsc1(gp + lane * 4 + c * 256);
    if (lane < 32) T.rp[7] = ldg4_ntsc1(gp + lane * 4 + 7 * 256);
    #pragma unroll
    for (int c = 0; c < 6; ++c) T.rt[c] = ldg4_ntsc1(gt + lane * 4 + c * 256);
    if (lane < 16) T.rt[6] = ldg4_ntsc1(gt + lane * 4 + 6 * 256);
}

__device__ static inline void drain_tile(const Tile& T, float* sp, float* st,
                                         int lane)
{
    #pragma unroll
    for (int c = 0; c < 7; ++c) *(f4*)(sp + lane * 4 + c * 256) = T.rp[c];
    if (lane < 32) *(f4*)(sp + lane * 4 + 7 * 256) = T.rp[7];
    #pragma unroll
    for (int c = 0; c < 6; ++c) *(f4*)(st + lane * 4 + c * 256) = T.rt[c];
    if (lane < 16) *(f4*)(st + lane * 4 + 6 * 256) = T.rt[6];
}

__device__ static inline float compute_cell(const float* lp, const float* lt)
{
    const float EPS = 1e-6f;

    const float tobj = lt[20];
    const float tx = lt[21], ty = lt[22], tw = lt[23], th = lt[24];

    const float t_x1 = tx - tw * 0.5f, t_x2 = tx + tw * 0.5f;
    const float t_y1 = ty - th * 0.5f, t_y2 = ty + th * 0.5f;
    const float t_area = fabsf((t_x2 - t_x1) * (t_y2 - t_y1));

    float iou[2];
    #pragma unroll
    for (int b = 0; b < 2; ++b) {
        const float bx = lp[NCLS + 5 * b + 1];
        const float by = lp[NCLS + 5 * b + 2];
        const float bw = lp[NCLS + 5 * b + 3];
        const float bh = lp[NCLS + 5 * b + 4];
        const float x1 = bx - bw * 0.5f, x2 = bx + bw * 0.5f;
        const float y1 = by - bh * 0.5f, y2 = by + bh * 0.5f;
        const float iw = fmaxf(fminf(x2, t_x2) - fmaxf(x1, t_x1), 0.0f);
        const float ih = fmaxf(fminf(y2, t_y2) - fmaxf(y1, t_y1), 0.0f);
        const float inter = iw * ih;
        const float a1 = fabsf((x2 - x1) * (y2 - y1));
        iou[b] = inter / (a1 + t_area - inter + EPS);
    }
    const int best = (iou[1] > iou[0]) ? 1 : 0;

    const float bconf = lp[NCLS + 5 * best + 0];
    const float bxv   = lp[NCLS + 5 * best + 1];
    const float byv   = lp[NCLS + 5 * best + 2];
    const float bwv   = lp[NCLS + 5 * best + 3];
    const float bhv   = lp[NCLS + 5 * best + 4];

    const float sgnw = (bwv > 0.f) ? 1.f : ((bwv < 0.f) ? -1.f : 0.f);
    const float sgnh = (bhv > 0.f) ? 1.f : ((bhv < 0.f) ? -1.f : 0.f);
    const float swv = sgnw * sqrtf(fabsf(bwv) + EPS);
    const float shv = sgnh * sqrtf(fabsf(bhv) + EPS);

    float d0 = tobj * bxv - tobj * tx;
    float d1 = tobj * byv - tobj * ty;
    float d2 = tobj * swv - sqrtf(fmaxf(tobj * tw, 0.0f));
    float d3 = tobj * shv - sqrtf(fmaxf(tobj * th, 0.0f));
    float box_loss = d0 * d0 + d1 * d1 + d2 * d2 + d3 * d3;

    const float noobj = 1.0f - tobj;
    float n0 = noobj * (lp[NCLS + 0] - tobj);
    float n1 = noobj * (lp[NCLS + 5] - tobj);
    float no_object_loss = n0 * n0 + n1 * n1;

    float od = tobj * (bconf - tobj);
    float object_loss = od * od;

    float class_loss = 0.0f;
    #pragma unroll
    for (int k = 0; k < NCLS; ++k) {
        float cd = tobj * (lp[k] - lt[k]);
        class_loss += cd * cd;
    }

    return 5.0f * box_loss + object_loss + 0.5f * no_object_loss + class_loss;
}

__global__ __launch_bounds__(64, 2) void yolo_main(
    const float* __restrict__ pred,
    const float* __restrict__ target,
    float* __restrict__ ws)
{
    __shared__ float sp[PRED_F];   // 7,680 B
    __shared__ float st[TGT_F];    // 6,400 B

    const int lane = threadIdx.x;
    const int blk  = blockIdx.x;
    const int n = (TILES - blk + GRID - 1) / GRID;   // 7 (blk<256) or 6

    Tile A, B;
    load_tile(A, pred, target, blk, lane);           // 15 in flight

    float acc = 0.0f;
    int i = 0;

    while (true) {
        // A holds tile i. Issue i+1 into B, THEN wait for A only (vmcnt 15).
        if (i + 1 < n) {
            load_tile(B, pred, target, blk + (i + 1) * GRID, lane);
            asm volatile("s_waitcnt vmcnt(15)" ::: "memory");
        } else {
            asm volatile("s_waitcnt vmcnt(0)" ::: "memory");
        }
        __builtin_amdgcn_sched_barrier(0);   // keep drain below the wait
        drain_tile(A, sp, st, lane);
        acc += compute_cell(sp + lane * 30, st + lane * 25);
        __asm__ volatile("" ::: "memory");   // LDS reads stay in this iter
        if (++i >= n) break;

        // B holds tile i. Mirror phase.
        if (i + 1 < n) {
            load_tile(A, pred, target, blk + (i + 1) * GRID, lane);
            asm volatile("s_waitcnt vmcnt(15)" ::: "memory");
        } else {
            asm volatile("s_waitcnt vmcnt(0)" ::: "memory");
        }
        __builtin_amdgcn_sched_barrier(0);
        drain_tile(B, sp, st, lane);
        acc += compute_cell(sp + lane * 30, st + lane * 25);
        __asm__ volatile("" ::: "memory");
        if (++i >= n) break;
    }

    // wave reduce + one spread atomic per wave
    #pragma unroll
    for (int off = 32; off > 0; off >>= 1)
        acc += __shfl_down(acc, off, 64);

    if (lane == 0)
        atomicAdd(&ws[blk & (SLOTS - 1)], acc);
}

__global__ __launch_bounds__(64) void yolo_reduce(
    const float* __restrict__ ws, float* __restrict__ out)
{
    const int lane = threadIdx.x;
    float s = ws[lane] + ws[lane + 64];
    #pragma unroll
    for (int off = 32; off > 0; off >>= 1)
        s += __shfl_down(s, off, 64);
    if (lane == 0) out[0] = s;
}

extern "C" void kernel_launch(void* const* d_in, const int* in_sizes, int n_in,
                              void* d_out, int out_size, void* d_ws, size_t ws_size,
                              hipStream_t stream) {
    const float* pred   = (const float*)d_in[0];
    const float* target = (const float*)d_in[1];
    float* ws  = (float*)d_ws;
    float* out = (float*)d_out;

    hipMemsetAsync(ws, 0, SLOTS * sizeof(float), stream);

    hipLaunchKernelGGL(yolo_main, dim3(GRID), dim3(64), 0, stream,
                       pred, target, ws);
    hipLaunchKernelGGL(yolo_reduce, dim3(1), dim3(64), 0, stream, ws, out);
}